// Round 21
// baseline (415.878 us; speedup 1.0000x reference)
//
#include <hip/hip_runtime.h>

#define Bq 2
#define Yq 512
#define Xq 512
#define NVOX 400000

typedef __bf16 bf16x8 __attribute__((ext_vector_type(8)));
typedef float f32x4 __attribute__((ext_vector_type(4)));
typedef float f32x16 __attribute__((ext_vector_type(16)));
typedef short s16x8 __attribute__((ext_vector_type(8)));
typedef short s16x2 __attribute__((ext_vector_type(2)));

__device__ __forceinline__ short f2bf_s(float f){
    return __builtin_bit_cast(short, static_cast<__bf16>(f));
}

__device__ __forceinline__ void atomic_pk_add_bf16(short* addr, unsigned data){
#if __has_builtin(__builtin_amdgcn_global_atomic_fadd_v2bf16)
    s16x2 v; v[0] = (short)(data & 0xffff); v[1] = (short)(data >> 16);
    __builtin_amdgcn_global_atomic_fadd_v2bf16(
        (__attribute__((address_space(1))) s16x2*)addr, v);
#else
    asm volatile("global_atomic_pk_add_bf16 %0, %1, off"
                 :: "v"(addr), "v"(data) : "memory");
#endif
}

// ---- fused: weight transpose/convert + per-cell count + dbf zero-fill ------
__global__ void kinit(const float* __restrict__ conv_w, const float* __restrict__ W_proj,
                      short* __restrict__ wTs, short* __restrict__ wpT,
                      const int* __restrict__ vc, unsigned* __restrict__ cnt,
                      unsigned char* __restrict__ act, uint4* __restrict__ dbf16){
    const int bx = blockIdx.x;
    if (bx < 672){
        int tid = bx*256 + threadIdx.x;
        if (tid < 9*128*128){
            int tap = tid >> 14; int r = tid & 16383; int co = r >> 7; int ci = r & 127;
            int g = ci >> 3, e = ci & 7;
            wTs[tap*16384 + co*128 + (((g & 8) | ((g & 7) ^ (co & 7))) << 3) + e] =
                f2bf_s(conv_w[tap*16384 + ci*128 + co]);
        }
        int e = tid - 9*128*128;
        if (e >= 0 && e < 128*192){
            int co = e / 192; int ci = e - co*192;
            wpT[e] = f2bf_s(W_proj[ci*128 + co]);
        }
    } else if (bx < 2235){
        int i = (bx - 672)*256 + threadIdx.x;
        if (i < NVOX){
            const int4 c = *reinterpret_cast<const int4*>(vc + i*4);
            int cell = (c.x*Yq + c.z)*Xq + c.w;
            act[cell] = 1;
            atomicAdd(&cnt[cell], 1u);
        }
    } else {
        const uint4 z = {0u,0u,0u,0u};
        const size_t b0 = (size_t)(bx - 2235)*4096 + threadIdx.x;
        #pragma unroll
        for (int j = 0; j < 16; ++j){
            size_t s = b0 + (size_t)j*256;
            if (s < 8454272ull) dbf16[s] = z;
        }
    }
}

// ---------------- projection + BN1 + ReLU + COALESCED scatter ----------
// A-fragments loaded DIRECTLY global->reg (vf has zero reuse — LDS staging
// was pure overhead; Common-mistake #7).  One barrier total.
__global__ void __launch_bounds__(256, 3)
kproj(const float* __restrict__ vf, const int* __restrict__ vc,
      const unsigned* __restrict__ cnt,
      const short* __restrict__ wpT, const float* __restrict__ bp,
      const float* __restrict__ g1, const float* __restrict__ be1,
      const float* __restrict__ mu1, const float* __restrict__ va1,
      short* __restrict__ dbf){
    __shared__ unsigned st[64*68];      // 17,408 B scatter-staging
    __shared__ int cellsPk[64];         // (multi<<30) | P*8 + (xp&7)
    const int t = threadIdx.x;
    const int v0 = blockIdx.x * 64;

    if (t < 64){
        int vi = v0 + t;
        int bi = vc[vi*4 + 0], yi = vc[vi*4 + 2], xi = vc[vi*4 + 3];
        unsigned cn = cnt[(bi*Yq + yi)*Xq + xi];
        int P = (bi*514 + (yi + 1))*514 + (xi + 1);
        cellsPk[t] = (P*8 + ((xi + 1) & 7)) | ((cn > 1) ? (1 << 30) : 0);
    }

    const int w  = t >> 6;
    const int l  = t & 63;
    const int lr = l & 15;
    const int q  = l >> 4;

    const short* wp_lane = wpT + (size_t)(w*32 + lr)*192 + q*8;
    bf16x8 bb[2][6];
    #pragma unroll
    for (int n = 0; n < 2; ++n)
        #pragma unroll
        for (int kc = 0; kc < 6; ++kc)
            bb[n][kc] = *reinterpret_cast<const bf16x8*>(wp_lane + n*16*192 + kc*32);

    const float4* vf4 = reinterpret_cast<const float4*>(vf);
    size_t rb[4];
    #pragma unroll
    for (int m = 0; m < 4; ++m)
        rb[m] = (size_t)(v0 + m*16 + lr)*48 + q*2;

    f32x4 acc[4][2] = {};
    #pragma unroll
    for (int kc = 0; kc < 6; ++kc){
        bf16x8 a[4];
        #pragma unroll
        for (int m = 0; m < 4; ++m){
            const float4* p = vf4 + rb[m] + kc*8;
            float4 x0 = p[0], x1 = p[1];
            s16x8 s;
            s[0]=f2bf_s(x0.x); s[1]=f2bf_s(x0.y); s[2]=f2bf_s(x0.z); s[3]=f2bf_s(x0.w);
            s[4]=f2bf_s(x1.x); s[5]=f2bf_s(x1.y); s[6]=f2bf_s(x1.z); s[7]=f2bf_s(x1.w);
            a[m] = __builtin_bit_cast(bf16x8, s);
        }
        #pragma unroll
        for (int m = 0; m < 4; ++m)
            #pragma unroll
            for (int n = 0; n < 2; ++n)
                acc[m][n] = __builtin_amdgcn_mfma_f32_16x16x32_bf16(a[m], bb[n][kc], acc[m][n], 0, 0, 0);
    }

    const int odd = lr & 1;
    #pragma unroll
    for (int n = 0; n < 2; ++n){
        int c = w*32 + n*16 + lr;
        float s1  = g1[c] * rsqrtf(va1[c] + 1e-5f);
        float sh1 = be1[c] + (bp[c] - mu1[c]) * s1;
        int jj = w*16 + n*8 + (lr >> 1);
        #pragma unroll
        for (int m = 0; m < 4; ++m){
            #pragma unroll
            for (int r = 0; r < 4; ++r){
                int vx = m*16 + q*4 + r;
                float val = fmaxf(fmaf(acc[m][n][r], s1, sh1), 0.f);
                float vp  = __shfl_xor(val, 1);
                if (!odd){
                    unsigned data = (unsigned)(unsigned short)f2bf_s(val)
                                  | ((unsigned)(unsigned short)f2bf_s(vp) << 16);
                    st[vx*68 + jj] = data;
                }
            }
        }
    }
    __syncthreads();    // st + cellsPk ready

    unsigned* dbf_u32 = reinterpret_cast<unsigned*>(dbf);
    #pragma unroll
    for (int i = 0; i < 16; ++i){
        int vv = w*16 + i;
        int pk = cellsPk[vv];
        int multi = pk >> 30;
        int P = (pk & 0x3fffffff) >> 3, xp7 = pk & 7;
        unsigned data = st[vv*68 + l];
        size_t idx = (size_t)P*64 + (((l >> 2) ^ xp7) << 2) + (l & 3);
        if (multi){
            if (data) atomic_pk_add_bf16((short*)(dbf_u32 + idx), data);
        } else {
            dbf_u32[idx] = data;
        }
    }
}

// ---------------- conv 3x3 + BN2 + ReLU + mask — persistent y-walk (R19) ----
__global__ void __launch_bounds__(512, 2)
kconv(const short* __restrict__ dbf, const short* __restrict__ wTs,
      const unsigned char* __restrict__ act, const float* __restrict__ cb,
      const float* __restrict__ g2, const float* __restrict__ be2,
      const float* __restrict__ mu2, const float* __restrict__ va2,
      float* __restrict__ out){
    __shared__ short Atile[5*1056*8];    // 84,480 B (5-slot ring)
    __shared__ short Bbuf[4][1024*8];    // 4 x 16,384 B  (total 150,016 B)
    const int t = threadIdx.x;
    const int bid = (blockIdx.x & 7)*64 + (blockIdx.x >> 3);
    const int b   = bid >> 8;
    const int rem = bid & 255;
    const int y0  = (rem >> 3) << 4;     // strip of 16 output rows
    const int x0  = (rem & 7) << 6;

    const int w   = t >> 6, l = t & 63;
    const int yy  = w >> 1, nn = w & 1;
    const int l31 = l & 31, hi = l >> 5;
    const int wbase16 = w*64*16;

    #define STAGE_B(BUF, H) do {                                              \
        const short* gb = wTs + (size_t)((H) >> 1)*16384 + ((H) & 1)*64;      \
        _Pragma("unroll")                                                     \
        for (int j = 0; j < 2; ++j){                                          \
            int S = j*512 + t;                                                \
            const short* gp = gb + (S >> 3)*128 + (S & 7)*8;                  \
            __builtin_amdgcn_global_load_lds(                                 \
                (const __attribute__((address_space(1))) void*)gp,            \
                (__attribute__((address_space(3))) void*)                    \
                    ((char*)Bbuf[BUF] + (size_t)(j*512*16) + wbase16), 16, 0, 0); \
        }                                                                     \
    } while(0)

    #define STAGE_A(R) do {                                                   \
        const int slot_ = (R) % 5;                                            \
        _Pragma("unroll")                                                     \
        for (int j = 0; j < 3; ++j){                                          \
            int S = j*512 + t;                                                \
            if (S < 1056){                                                    \
                const short* gp = dbf +                                       \
                    ((size_t)((b*514 + (y0 + (R)))*514 + x0)*16 + S)*8;       \
                __builtin_amdgcn_global_load_lds(                             \
                    (const __attribute__((address_space(1))) void*)gp,        \
                    (__attribute__((address_space(3))) void*)                \
                        ((char*)Atile + (size_t)(slot_*1056 + j*512 + w*64)*16), \
                    16, 0, 0);                                                \
            }                                                                 \
        }                                                                     \
    } while(0)

    STAGE_B(0, 0);
    STAGE_B(1, 1);
    STAGE_A(0); STAGE_A(1); STAGE_A(2); STAGE_A(3); STAGE_A(4);

    const int bReadBase = (nn*64 + l31)*64;
    const int bXor = l31 & 7;

    float s2c[2], sh2c[2];
    #pragma unroll
    for (int ni = 0; ni < 2; ++ni){
        int c = nn*64 + ni*32 + l31;
        s2c[ni]  = g2[c] * rsqrtf(va2[c] + 1e-3f);
        sh2c[ni] = be2[c] + (cb[c] - mu2[c]) * s2c[ni];
    }

    #pragma unroll 1
    for (int g = 0; g < 4; ++g){
        f32x16 acc[2][2] = {};
        if (g >= 1){
            __builtin_amdgcn_sched_barrier(0);
            __builtin_amdgcn_s_barrier();
            __builtin_amdgcn_sched_barrier(0);
            STAGE_A(4*g + 3);
        }
        #pragma unroll
        for (int p = 0; p < 18; ++p){
            if ((p & 1) == 0){
                __builtin_amdgcn_sched_barrier(0);
                asm volatile("s_waitcnt vmcnt(0)" ::: "memory");
                __builtin_amdgcn_s_barrier();
                __builtin_amdgcn_sched_barrier(0);
                const int P = g*18 + p;
                if (P + 2 < 72) STAGE_B((2*g + p + 2) & 3, (p + 2) % 18);
                if (P + 3 < 72) STAGE_B((2*g + p + 3) & 3, (p + 3) % 18);
                if (p == 0 && g >= 1)           STAGE_A(4*g + 4);
                if (p == 6)                     STAGE_A(4*g + 5);
                if (p == 12 && (4*g + 6) <= 17) STAGE_A(4*g + 6);
                __builtin_amdgcn_sched_barrier(0);
            }
            const short* Bc = Bbuf[(2*g + p) & 3];
            const int tap = p >> 1, hh = p & 1;
            const int ky = tap / 3, kx = tap - ky*3;
            const int R  = 4*g + yy + ky;
            const int rowp = R % 5;
            const int p0 = l31 + kx, p1 = p0 + 32;
            const int base0 = (rowp*1056 + p0*16)*8;
            const int base1 = (rowp*1056 + p1*16)*8;
            const int pk7 = p0 & 7;
            #pragma unroll
            for (int kc = 0; kc < 4; ++kc){
                const int ks  = kc*2 + hi;
                const int q   = ((hh*8 + ks) ^ pk7) << 3;
                const int qb  = (ks ^ bXor) << 3;
                bf16x8 a0 = *reinterpret_cast<const bf16x8*>(&Atile[base0 + q]);
                bf16x8 a1 = *reinterpret_cast<const bf16x8*>(&Atile[base1 + q]);
                bf16x8 b0 = *reinterpret_cast<const bf16x8*>(&Bc[bReadBase + qb]);
                bf16x8 b1 = *reinterpret_cast<const bf16x8*>(&Bc[bReadBase + 2048 + qb]);
                acc[0][0] = __builtin_amdgcn_mfma_f32_32x32x16_bf16(a0, b0, acc[0][0], 0, 0, 0);
                acc[0][1] = __builtin_amdgcn_mfma_f32_32x32x16_bf16(a0, b1, acc[0][1], 0, 0, 0);
                acc[1][0] = __builtin_amdgcn_mfma_f32_32x32x16_bf16(a1, b0, acc[1][0], 0, 0, 0);
                acc[1][1] = __builtin_amdgcn_mfma_f32_32x32x16_bf16(a1, b1, acc[1][1], 0, 0, 0);
            }
        }
        const int yg = y0 + 4*g + yy;
        const size_t rowcell = (size_t)(b*Yq + yg)*Xq + x0;
        #pragma unroll
        for (int ni = 0; ni < 2; ++ni){
            int c = nn*64 + ni*32 + l31;
            #pragma unroll
            for (int mi = 0; mi < 2; ++mi){
                #pragma unroll
                for (int r = 0; r < 16; ++r){
                    int pos = mi*32 + (r & 3) + ((r >> 2) << 3) + hi*4;
                    size_t cell = rowcell + pos;
                    float v = act[cell] ? fmaxf(fmaf(acc[mi][ni][r], s2c[ni], sh2c[ni]), 0.f) : 0.f;
                    out[cell*128 + c] = v;
                }
            }
        }
    }
    #undef STAGE_A
    #undef STAGE_B
}

extern "C" void kernel_launch(void* const* d_in, const int* in_sizes, int n_in,
                              void* d_out, int out_size, void* d_ws, size_t ws_size,
                              hipStream_t stream){
    const float* vf  = (const float*)d_in[0];
    const int*   vc  = (const int*)  d_in[1];
    const float* Wp  = (const float*)d_in[2];
    const float* bp  = (const float*)d_in[3];
    const float* g1  = (const float*)d_in[4];
    const float* be1 = (const float*)d_in[5];
    const float* mu1 = (const float*)d_in[6];
    const float* va1 = (const float*)d_in[7];
    const float* cw  = (const float*)d_in[8];
    const float* cb  = (const float*)d_in[9];
    const float* g2  = (const float*)d_in[10];
    const float* be2 = (const float*)d_in[11];
    const float* mu2 = (const float*)d_in[12];
    const float* va2 = (const float*)d_in[13];
    float* out = (float*)d_out;
    char* ws = (char*)d_ws;

    // ws layout (bytes):
    //   dbf bf16 [2][514][514][128] : 135,268,352 @ 0   (padded, pre-swizzled)
    //   act  u8  [2][512][512]      :     524,288 @ 135,268,352
    //   wTs  bf16 [9][128][128]     :     294,912 @ 135,792,640  (pre-swizzled)
    //   wpT  bf16 [128][192]        :      49,152 @ 136,087,552
    //   cnt  u32 [2][512][512]      :   2,097,152 @ 136,136,704  (end 138,233,856)
    if (ws_size < 138233856ull) return;
    short* dbf = (short*)ws;
    unsigned char* act = (unsigned char*)(ws + 135268352);
    short* wTs = (short*)(ws + 135792640);
    short* wpT = (short*)(ws + 136087552);
    unsigned* cnt = (unsigned*)(ws + 136136704);

    hipMemsetAsync(act, 0, 524288, stream);
    hipMemsetAsync(cnt, 0, 2097152, stream);
    kinit<<<4300, 256, 0, stream>>>(cw, Wp, wTs, wpT, vc, cnt, act, (uint4*)dbf);
    kproj<<<6250, 256, 0, stream>>>(vf, vc, cnt, wpT, bp, g1, be1, mu1, va1, dbf);
    kconv<<<512, 512, 0, stream>>>(dbf, wTs, act, cb, g2, be2, mu2, va2, out);
}

// Round 22
// 342.527 us; speedup vs baseline: 1.2141x; 1.2141x over previous
//
#include <hip/hip_runtime.h>

#define Bq 2
#define Yq 512
#define Xq 512
#define NVOX 400000

typedef __bf16 bf16x8 __attribute__((ext_vector_type(8)));
typedef float f32x4 __attribute__((ext_vector_type(4)));
typedef float f32x16 __attribute__((ext_vector_type(16)));
typedef short s16x8 __attribute__((ext_vector_type(8)));
typedef short s16x2 __attribute__((ext_vector_type(2)));

__device__ __forceinline__ short f2bf_s(float f){
    return __builtin_bit_cast(short, static_cast<__bf16>(f));
}

__device__ __forceinline__ void atomic_pk_add_bf16(short* addr, unsigned data){
#if __has_builtin(__builtin_amdgcn_global_atomic_fadd_v2bf16)
    s16x2 v; v[0] = (short)(data & 0xffff); v[1] = (short)(data >> 16);
    __builtin_amdgcn_global_atomic_fadd_v2bf16(
        (__attribute__((address_space(1))) s16x2*)addr, v);
#else
    asm volatile("global_atomic_pk_add_bf16 %0, %1, off"
                 :: "v"(addr), "v"(data) : "memory");
#endif
}

// ---- fused: weight transpose/convert + per-cell count + dbf zero-fill ------
// blocks [0,672): wTs/wpT prep.  [672,2235): voxel count + act mask.
// [2235,4300): zero dbf (135,268,352 B = 8,454,272 uint4 slots) — overlaps
// the (independent) prep/count work, replacing a serial 135MB memset.
__global__ void kinit(const float* __restrict__ conv_w, const float* __restrict__ W_proj,
                      short* __restrict__ wTs, short* __restrict__ wpT,
                      const int* __restrict__ vc, unsigned* __restrict__ cnt,
                      unsigned char* __restrict__ act, uint4* __restrict__ dbf16){
    const int bx = blockIdx.x;
    if (bx < 672){
        int tid = bx*256 + threadIdx.x;
        if (tid < 9*128*128){
            int tap = tid >> 14; int r = tid & 16383; int co = r >> 7; int ci = r & 127;
            int g = ci >> 3, e = ci & 7;
            wTs[tap*16384 + co*128 + (((g & 8) | ((g & 7) ^ (co & 7))) << 3) + e] =
                f2bf_s(conv_w[tap*16384 + ci*128 + co]);
        }
        int e = tid - 9*128*128;
        if (e >= 0 && e < 128*192){
            int co = e / 192; int ci = e - co*192;
            wpT[e] = f2bf_s(W_proj[ci*128 + co]);
        }
    } else if (bx < 2235){
        int i = (bx - 672)*256 + threadIdx.x;
        if (i < NVOX){
            const int4 c = *reinterpret_cast<const int4*>(vc + i*4);
            int cell = (c.x*Yq + c.z)*Xq + c.w;
            act[cell] = 1;
            atomicAdd(&cnt[cell], 1u);
        }
    } else {
        const uint4 z = {0u,0u,0u,0u};
        const size_t b0 = (size_t)(bx - 2235)*4096 + threadIdx.x;
        #pragma unroll
        for (int j = 0; j < 16; ++j){
            size_t s = b0 + (size_t)j*256;
            if (s < 8454272ull) dbf16[s] = z;
        }
    }
}

// ---------------- projection + BN1 + ReLU + COALESCED scatter ----------
// LDS-staged A (validated load-bearing by R21 ablation: direct global->reg
// triggers allocator demotion, 130 -> 215 us).
__global__ void __launch_bounds__(256, 2)
kproj(const float* __restrict__ vf, const int* __restrict__ vc,
      const unsigned* __restrict__ cnt,
      const short* __restrict__ wpT, const float* __restrict__ bp,
      const float* __restrict__ g1, const float* __restrict__ be1,
      const float* __restrict__ mu1, const float* __restrict__ va1,
      short* __restrict__ dbf){
    __shared__ char smem[64*200*2];     // A (bf16 stage) ∪ st (u32 pairs)
    __shared__ int cellsPk[64];         // (multi<<30) | P*8 + (xp&7)
    short*    A  = (short*)smem;
    unsigned* st = (unsigned*)smem;     // st[vx*68 + j]
    const int t = threadIdx.x;
    const int v0 = blockIdx.x * 64;

    const float4* vf4 = reinterpret_cast<const float4*>(vf);
    #pragma unroll
    for (int j = 0; j < 12; ++j){
        int i = t + j*256;
        int v = i / 48, kq = i - v*48;
        float4 x = vf4[(size_t)(v0 + v)*48 + kq];
        short4 s; s.x=f2bf_s(x.x); s.y=f2bf_s(x.y); s.z=f2bf_s(x.z); s.w=f2bf_s(x.w);
        *reinterpret_cast<short4*>(&A[v*200 + kq*4]) = s;
    }
    if (t < 64){
        int vi = v0 + t;
        int bi = vc[vi*4 + 0], yi = vc[vi*4 + 2], xi = vc[vi*4 + 3];
        unsigned cn = cnt[(bi*Yq + yi)*Xq + xi];
        int P = (bi*514 + (yi + 1))*514 + (xi + 1);
        cellsPk[t] = (P*8 + ((xi + 1) & 7)) | ((cn > 1) ? (1 << 30) : 0);
    }
    __syncthreads();

    const int w  = t >> 6;
    const int l  = t & 63;
    const int lr = l & 15;
    const int q  = l >> 4;

    const short* wp_lane = wpT + (size_t)(w*32 + lr)*192 + q*8;
    bf16x8 bb[2][6];
    #pragma unroll
    for (int n = 0; n < 2; ++n)
        #pragma unroll
        for (int kc = 0; kc < 6; ++kc)
            bb[n][kc] = *reinterpret_cast<const bf16x8*>(wp_lane + n*16*192 + kc*32);

    f32x4 acc[4][2] = {};
    #pragma unroll
    for (int kc = 0; kc < 6; ++kc){
        bf16x8 a[4];
        #pragma unroll
        for (int m = 0; m < 4; ++m)
            a[m] = *reinterpret_cast<const bf16x8*>(&A[(m*16 + lr)*200 + kc*32 + q*8]);
        #pragma unroll
        for (int m = 0; m < 4; ++m)
            #pragma unroll
            for (int n = 0; n < 2; ++n)
                acc[m][n] = __builtin_amdgcn_mfma_f32_16x16x32_bf16(a[m], bb[n][kc], acc[m][n], 0, 0, 0);
    }

    __syncthreads();
    const int odd = lr & 1;
    #pragma unroll
    for (int n = 0; n < 2; ++n){
        int c = w*32 + n*16 + lr;
        float s1  = g1[c] * rsqrtf(va1[c] + 1e-5f);
        float sh1 = be1[c] + (bp[c] - mu1[c]) * s1;
        int jj = w*16 + n*8 + (lr >> 1);
        #pragma unroll
        for (int m = 0; m < 4; ++m){
            #pragma unroll
            for (int r = 0; r < 4; ++r){
                int vx = m*16 + q*4 + r;
                float val = fmaxf(fmaf(acc[m][n][r], s1, sh1), 0.f);
                float vp  = __shfl_xor(val, 1);
                if (!odd){
                    unsigned data = (unsigned)(unsigned short)f2bf_s(val)
                                  | ((unsigned)(unsigned short)f2bf_s(vp) << 16);
                    st[vx*68 + jj] = data;
                }
            }
        }
    }
    __syncthreads();

    unsigned* dbf_u32 = reinterpret_cast<unsigned*>(dbf);
    #pragma unroll
    for (int i = 0; i < 16; ++i){
        int vv = w*16 + i;
        int pk = cellsPk[vv];
        int multi = pk >> 30;
        int P = (pk & 0x3fffffff) >> 3, xp7 = pk & 7;
        unsigned data = st[vv*68 + l];
        size_t idx = (size_t)P*64 + (((l >> 2) ^ xp7) << 2) + (l & 3);
        if (multi){
            if (data) atomic_pk_add_bf16((short*)(dbf_u32 + idx), data);
        } else {
            dbf_u32[idx] = data;
        }
    }
}

// ---------------- conv 3x3 + BN2 + ReLU + mask — persistent y-walk (R19) ----
__global__ void __launch_bounds__(512, 2)
kconv(const short* __restrict__ dbf, const short* __restrict__ wTs,
      const unsigned char* __restrict__ act, const float* __restrict__ cb,
      const float* __restrict__ g2, const float* __restrict__ be2,
      const float* __restrict__ mu2, const float* __restrict__ va2,
      float* __restrict__ out){
    __shared__ short Atile[5*1056*8];    // 84,480 B (5-slot ring)
    __shared__ short Bbuf[4][1024*8];    // 4 x 16,384 B  (total 150,016 B)
    const int t = threadIdx.x;
    const int bid = (blockIdx.x & 7)*64 + (blockIdx.x >> 3);
    const int b   = bid >> 8;
    const int rem = bid & 255;
    const int y0  = (rem >> 3) << 4;     // strip of 16 output rows
    const int x0  = (rem & 7) << 6;

    const int w   = t >> 6, l = t & 63;
    const int yy  = w >> 1, nn = w & 1;
    const int l31 = l & 31, hi = l >> 5;
    const int wbase16 = w*64*16;

    #define STAGE_B(BUF, H) do {                                              \
        const short* gb = wTs + (size_t)((H) >> 1)*16384 + ((H) & 1)*64;      \
        _Pragma("unroll")                                                     \
        for (int j = 0; j < 2; ++j){                                          \
            int S = j*512 + t;                                                \
            const short* gp = gb + (S >> 3)*128 + (S & 7)*8;                  \
            __builtin_amdgcn_global_load_lds(                                 \
                (const __attribute__((address_space(1))) void*)gp,            \
                (__attribute__((address_space(3))) void*)                    \
                    ((char*)Bbuf[BUF] + (size_t)(j*512*16) + wbase16), 16, 0, 0); \
        }                                                                     \
    } while(0)

    #define STAGE_A(R) do {                                                   \
        const int slot_ = (R) % 5;                                            \
        _Pragma("unroll")                                                     \
        for (int j = 0; j < 3; ++j){                                          \
            int S = j*512 + t;                                                \
            if (S < 1056){                                                    \
                const short* gp = dbf +                                       \
                    ((size_t)((b*514 + (y0 + (R)))*514 + x0)*16 + S)*8;       \
                __builtin_amdgcn_global_load_lds(                             \
                    (const __attribute__((address_space(1))) void*)gp,        \
                    (__attribute__((address_space(3))) void*)                \
                        ((char*)Atile + (size_t)(slot_*1056 + j*512 + w*64)*16), \
                    16, 0, 0);                                                \
            }                                                                 \
        }                                                                     \
    } while(0)

    STAGE_B(0, 0);
    STAGE_B(1, 1);
    STAGE_A(0); STAGE_A(1); STAGE_A(2); STAGE_A(3); STAGE_A(4);

    const int bReadBase = (nn*64 + l31)*64;
    const int bXor = l31 & 7;

    float s2c[2], sh2c[2];
    #pragma unroll
    for (int ni = 0; ni < 2; ++ni){
        int c = nn*64 + ni*32 + l31;
        s2c[ni]  = g2[c] * rsqrtf(va2[c] + 1e-3f);
        sh2c[ni] = be2[c] + (cb[c] - mu2[c]) * s2c[ni];
    }

    #pragma unroll 1
    for (int g = 0; g < 4; ++g){
        f32x16 acc[2][2] = {};
        if (g >= 1){
            __builtin_amdgcn_sched_barrier(0);
            __builtin_amdgcn_s_barrier();
            __builtin_amdgcn_sched_barrier(0);
            STAGE_A(4*g + 3);
        }
        #pragma unroll
        for (int p = 0; p < 18; ++p){
            if ((p & 1) == 0){
                __builtin_amdgcn_sched_barrier(0);
                asm volatile("s_waitcnt vmcnt(0)" ::: "memory");
                __builtin_amdgcn_s_barrier();
                __builtin_amdgcn_sched_barrier(0);
                const int P = g*18 + p;
                if (P + 2 < 72) STAGE_B((2*g + p + 2) & 3, (p + 2) % 18);
                if (P + 3 < 72) STAGE_B((2*g + p + 3) & 3, (p + 3) % 18);
                if (p == 0 && g >= 1)           STAGE_A(4*g + 4);
                if (p == 6)                     STAGE_A(4*g + 5);
                if (p == 12 && (4*g + 6) <= 17) STAGE_A(4*g + 6);
                __builtin_amdgcn_sched_barrier(0);
            }
            const short* Bc = Bbuf[(2*g + p) & 3];
            const int tap = p >> 1, hh = p & 1;
            const int ky = tap / 3, kx = tap - ky*3;
            const int R  = 4*g + yy + ky;
            const int rowp = R % 5;
            const int p0 = l31 + kx, p1 = p0 + 32;
            const int base0 = (rowp*1056 + p0*16)*8;
            const int base1 = (rowp*1056 + p1*16)*8;
            const int pk7 = p0 & 7;
            #pragma unroll
            for (int kc = 0; kc < 4; ++kc){
                const int ks  = kc*2 + hi;
                const int q   = ((hh*8 + ks) ^ pk7) << 3;
                const int qb  = (ks ^ bXor) << 3;
                bf16x8 a0 = *reinterpret_cast<const bf16x8*>(&Atile[base0 + q]);
                bf16x8 a1 = *reinterpret_cast<const bf16x8*>(&Atile[base1 + q]);
                bf16x8 b0 = *reinterpret_cast<const bf16x8*>(&Bc[bReadBase + qb]);
                bf16x8 b1 = *reinterpret_cast<const bf16x8*>(&Bc[bReadBase + 2048 + qb]);
                acc[0][0] = __builtin_amdgcn_mfma_f32_32x32x16_bf16(a0, b0, acc[0][0], 0, 0, 0);
                acc[0][1] = __builtin_amdgcn_mfma_f32_32x32x16_bf16(a0, b1, acc[0][1], 0, 0, 0);
                acc[1][0] = __builtin_amdgcn_mfma_f32_32x32x16_bf16(a1, b0, acc[1][0], 0, 0, 0);
                acc[1][1] = __builtin_amdgcn_mfma_f32_32x32x16_bf16(a1, b1, acc[1][1], 0, 0, 0);
            }
        }
        const int yg = y0 + 4*g + yy;
        const size_t rowcell = (size_t)(b*Yq + yg)*Xq + x0;
        #pragma unroll
        for (int ni = 0; ni < 2; ++ni){
            int c = nn*64 + ni*32 + l31;
            #pragma unroll
            for (int mi = 0; mi < 2; ++mi){
                #pragma unroll
                for (int r = 0; r < 16; ++r){
                    int pos = mi*32 + (r & 3) + ((r >> 2) << 3) + hi*4;
                    size_t cell = rowcell + pos;
                    float v = act[cell] ? fmaxf(fmaf(acc[mi][ni][r], s2c[ni], sh2c[ni]), 0.f) : 0.f;
                    out[cell*128 + c] = v;
                }
            }
        }
    }
    #undef STAGE_A
    #undef STAGE_B
}

extern "C" void kernel_launch(void* const* d_in, const int* in_sizes, int n_in,
                              void* d_out, int out_size, void* d_ws, size_t ws_size,
                              hipStream_t stream){
    const float* vf  = (const float*)d_in[0];
    const int*   vc  = (const int*)  d_in[1];
    const float* Wp  = (const float*)d_in[2];
    const float* bp  = (const float*)d_in[3];
    const float* g1  = (const float*)d_in[4];
    const float* be1 = (const float*)d_in[5];
    const float* mu1 = (const float*)d_in[6];
    const float* va1 = (const float*)d_in[7];
    const float* cw  = (const float*)d_in[8];
    const float* cb  = (const float*)d_in[9];
    const float* g2  = (const float*)d_in[10];
    const float* be2 = (const float*)d_in[11];
    const float* mu2 = (const float*)d_in[12];
    const float* va2 = (const float*)d_in[13];
    float* out = (float*)d_out;
    char* ws = (char*)d_ws;

    // ws layout (bytes):
    //   dbf bf16 [2][514][514][128] : 135,268,352 @ 0   (padded, pre-swizzled)
    //   act  u8  [2][512][512]      :     524,288 @ 135,268,352
    //   wTs  bf16 [9][128][128]     :     294,912 @ 135,792,640  (pre-swizzled)
    //   wpT  bf16 [128][192]        :      49,152 @ 136,087,552
    //   cnt  u32 [2][512][512]      :   2,097,152 @ 136,136,704  (end 138,233,856)
    if (ws_size < 138233856ull) return;
    short* dbf = (short*)ws;
    unsigned char* act = (unsigned char*)(ws + 135268352);
    short* wTs = (short*)(ws + 135792640);
    short* wpT = (short*)(ws + 136087552);
    unsigned* cnt = (unsigned*)(ws + 136136704);

    hipMemsetAsync(act, 0, 524288, stream);
    hipMemsetAsync(cnt, 0, 2097152, stream);
    kinit<<<4300, 256, 0, stream>>>(cw, Wp, wTs, wpT, vc, cnt, act, (uint4*)dbf);
    kproj<<<6250, 256, 0, stream>>>(vf, vc, cnt, wpT, bp, g1, be1, mu1, va1, dbf);
    kconv<<<512, 512, 0, stream>>>(dbf, wTs, act, cb, g2, be2, mu2, va2, out);
}